// Round 1
// baseline (40.433 us; speedup 1.0000x reference)
//
#include <hip/hip_runtime.h>
#include <hip/hip_bf16.h>
#include <math.h>

// Problem constants (from reference setup_inputs): B=32, N=256, D=32.
#define BB 32
#define NN 256
#define DD 32
#define SPLIT 4                 // j-dimension split per (batch,type)
#define JCHUNK (NN / SPLIT)     // 64
#define NPART (BB * 3 * SPLIT)  // 384 partials

// Kernel 1: each block computes a partial sum of exp(-w*||a_i - b_j||/D)
// over all i in [0,256) and j in a 64-wide chunk, for one (batch, type).
// type 0: (x,x)  -> +1 weight
// type 1: (y,y)  -> +1 weight
// type 2: (x,y)  -> -2 weight
__global__ __launch_bounds__(NN) void mmd_partial_kernel(
    const float* __restrict__ x, const float* __restrict__ y,
    const float* __restrict__ w, float* __restrict__ partials) {
    const int blk  = blockIdx.x;
    const int s    = blk & (SPLIT - 1);
    const int bt   = blk / SPLIT;
    const int type = bt % 3;
    const int b    = bt / 3;

    const float* Arow_base = (type == 1) ? y : x;   // rows (i)
    const float* Bcol_base = (type == 0) ? x : y;   // cols (j)

    const int i = threadIdx.x;   // one A-row per thread (N == blockDim.x)

    // A row in registers + |a|^2
    float a[DD];
    float a2 = 0.f;
    {
        const float* ar = Arow_base + ((size_t)b * NN + i) * DD;
        #pragma unroll
        for (int d = 0; d < DD; ++d) {
            a[d] = ar[d];
            a2 = fmaf(a[d], a[d], a2);
        }
    }

    // Stage the 64-row B chunk in LDS, padded to 33 floats to kill bank
    // conflicts on the per-row y2 pass (dot-loop reads are broadcast).
    __shared__ float bs[JCHUNK][DD + 1];
    __shared__ float b2s[JCHUNK];
    {
        const float* bb = Bcol_base + ((size_t)b * NN + s * JCHUNK) * DD;
        for (int t = threadIdx.x; t < JCHUNK * DD; t += blockDim.x) {
            bs[t / DD][t % DD] = bb[t];
        }
    }
    __syncthreads();
    if (threadIdx.x < JCHUNK) {
        const int j = threadIdx.x;
        float s2 = 0.f;
        #pragma unroll
        for (int d = 0; d < DD; ++d) s2 = fmaf(bs[j][d], bs[j][d], s2);
        b2s[j] = s2;
    }
    __syncthreads();

    const float wv = w[b];
    const float negw_over_d = -wv * (1.0f / (float)DD);

    float acc = 0.f;
    #pragma unroll 4
    for (int j = 0; j < JCHUNK; ++j) {
        float dot = 0.f;
        #pragma unroll
        for (int d = 0; d < DD; ++d) dot = fmaf(a[d], bs[j][d], dot);
        float sq = a2 + b2s[j] - 2.0f * dot;
        sq = fmaxf(sq, 0.0f);
        float nrm = fmaxf(sqrtf(sq), 1.0e-4f);
        acc += __expf(negw_over_d * nrm);
    }

    // Deterministic block reduction: wave64 shuffle tree, then fixed-order
    // cross-wave sum by thread 0.
    #pragma unroll
    for (int off = 32; off > 0; off >>= 1) acc += __shfl_down(acc, off, 64);
    __shared__ float red[NN / 64];
    if ((threadIdx.x & 63) == 0) red[threadIdx.x >> 6] = acc;
    __syncthreads();
    if (threadIdx.x == 0) {
        float bsum = 0.f;
        #pragma unroll
        for (int wv_i = 0; wv_i < NN / 64; ++wv_i) bsum += red[wv_i];
        const float weight = (type == 2) ? -2.0f : 1.0f;
        const float scale = weight / ((float)NN * (float)NN * (float)BB);
        partials[blk] = bsum * scale;
    }
}

// Kernel 2: deterministic final reduction of NPART partials in double.
__global__ __launch_bounds__(256) void mmd_reduce_kernel(
    const float* __restrict__ partials, float* __restrict__ out) {
    double acc = 0.0;
    for (int t = threadIdx.x; t < NPART; t += blockDim.x)
        acc += (double)partials[t];
    #pragma unroll
    for (int off = 32; off > 0; off >>= 1) acc += __shfl_down(acc, off, 64);
    __shared__ double red[4];
    if ((threadIdx.x & 63) == 0) red[threadIdx.x >> 6] = acc;
    __syncthreads();
    if (threadIdx.x == 0)
        out[0] = (float)(((red[0] + red[1]) + (red[2] + red[3])));
}

extern "C" void kernel_launch(void* const* d_in, const int* in_sizes, int n_in,
                              void* d_out, int out_size, void* d_ws, size_t ws_size,
                              hipStream_t stream) {
    const float* x = (const float*)d_in[0];
    const float* y = (const float*)d_in[1];
    const float* w = (const float*)d_in[2];
    float* out = (float*)d_out;
    float* partials = (float*)d_ws;  // NPART floats

    mmd_partial_kernel<<<NPART, NN, 0, stream>>>(x, y, w, partials);
    mmd_reduce_kernel<<<1, 256, 0, stream>>>(partials, out);
}

// Round 2
// 27.111 us; speedup vs baseline: 1.4914x; 1.4914x over previous
//
#include <hip/hip_runtime.h>
#include <hip/hip_bf16.h>
#include <math.h>

// Problem constants (from reference setup_inputs): B=32, N=256, D=32.
#define BB 32
#define NN 256
#define DD 32
#define RPT 4                    // A-rows per thread (held in registers)
#define TPB 64                   // one wave per block; 64*RPT = 256 = all rows
#define SPLIT 16                 // j-dimension split per (batch,type)
#define JCHUNK (NN / SPLIT)      // 16 j's per block
#define NPART (BB * 3 * SPLIT)   // 1536 partials

// type 0: (x,x) weight +1 | type 1: (y,y) weight +1 | type 2: (x,y) weight -2
__global__ __launch_bounds__(TPB) void mmd_partial_kernel(
    const float* __restrict__ x, const float* __restrict__ y,
    const float* __restrict__ w, float* __restrict__ partials) {
    const int blk  = blockIdx.x;
    const int s    = blk & (SPLIT - 1);
    const int bt   = blk / SPLIT;
    const int type = bt % 3;
    const int b    = bt / 3;
    const int tid  = threadIdx.x;

    const float* Arow_base = (type == 1) ? y : x;   // rows (i)
    const float* Bcol_base = (type == 0) ? x : y;   // cols (j)

    // 4 A-rows per thread in registers (+ their |a|^2), rows i = r*64 + tid.
    float4 a[RPT][DD / 4];
    float a2[RPT];
    #pragma unroll
    for (int r = 0; r < RPT; ++r) {
        const int i = r * TPB + tid;
        const float4* ar =
            (const float4*)(Arow_base + ((size_t)b * NN + i) * DD);
        float4 s2 = make_float4(0.f, 0.f, 0.f, 0.f);
        #pragma unroll
        for (int k = 0; k < DD / 4; ++k) {
            float4 v = ar[k];
            a[r][k] = v;
            s2.x = fmaf(v.x, v.x, s2.x);
            s2.y = fmaf(v.y, v.y, s2.y);
            s2.z = fmaf(v.z, v.z, s2.z);
            s2.w = fmaf(v.w, v.w, s2.w);
        }
        a2[r] = (s2.x + s2.y) + (s2.z + s2.w);
    }

    // Stage the JCHUNK B-rows in LDS as float4 (read back with ds_read_b128
    // broadcast — uniform address, conflict-free).
    __shared__ float4 bs4[JCHUNK * (DD / 4)];
    __shared__ float b2s[JCHUNK];
    {
        const float4* bb =
            (const float4*)(Bcol_base + ((size_t)b * NN + s * JCHUNK) * DD);
        for (int t = tid; t < JCHUNK * (DD / 4); t += TPB) bs4[t] = bb[t];
    }
    __syncthreads();
    if (tid < JCHUNK) {
        float4 s2 = make_float4(0.f, 0.f, 0.f, 0.f);
        #pragma unroll
        for (int k = 0; k < DD / 4; ++k) {
            float4 v = bs4[tid * (DD / 4) + k];
            s2.x = fmaf(v.x, v.x, s2.x);
            s2.y = fmaf(v.y, v.y, s2.y);
            s2.z = fmaf(v.z, v.z, s2.z);
            s2.w = fmaf(v.w, v.w, s2.w);
        }
        b2s[tid] = (s2.x + s2.y) + (s2.z + s2.w);
    }
    __syncthreads();

    const float negw_over_d = -w[b] * (1.0f / (float)DD);

    float acc[RPT] = {0.f, 0.f, 0.f, 0.f};
    #pragma unroll 4
    for (int j = 0; j < JCHUNK; ++j) {
        const float b2 = b2s[j];
        float4 dv[RPT];
        #pragma unroll
        for (int r = 0; r < RPT; ++r) dv[r] = make_float4(0.f, 0.f, 0.f, 0.f);
        #pragma unroll
        for (int k = 0; k < DD / 4; ++k) {
            const float4 bv = bs4[j * (DD / 4) + k];
            #pragma unroll
            for (int r = 0; r < RPT; ++r) {
                dv[r].x = fmaf(a[r][k].x, bv.x, dv[r].x);
                dv[r].y = fmaf(a[r][k].y, bv.y, dv[r].y);
                dv[r].z = fmaf(a[r][k].z, bv.z, dv[r].z);
                dv[r].w = fmaf(a[r][k].w, bv.w, dv[r].w);
            }
        }
        #pragma unroll
        for (int r = 0; r < RPT; ++r) {
            const float dot = (dv[r].x + dv[r].y) + (dv[r].z + dv[r].w);
            float sq = fmaf(-2.0f, dot, a2[r] + b2);
            sq = fmaxf(sq, 0.0f);
            const float nrm = fmaxf(__builtin_amdgcn_sqrtf(sq), 1.0e-4f);
            acc[r] += __expf(negw_over_d * nrm);
        }
    }

    // Deterministic wave64 reduction; lane 0 writes the scaled partial.
    float tsum = (acc[0] + acc[1]) + (acc[2] + acc[3]);
    #pragma unroll
    for (int off = 32; off > 0; off >>= 1) tsum += __shfl_down(tsum, off, 64);
    if (tid == 0) {
        const float weight = (type == 2) ? -2.0f : 1.0f;
        const float scale = weight / ((float)NN * (float)NN * (float)BB);
        partials[blk] = tsum * scale;
    }
}

// Final deterministic reduction of NPART partials in double.
__global__ __launch_bounds__(256) void mmd_reduce_kernel(
    const float* __restrict__ partials, float* __restrict__ out) {
    double acc = 0.0;
    for (int t = threadIdx.x; t < NPART; t += 256) acc += (double)partials[t];
    #pragma unroll
    for (int off = 32; off > 0; off >>= 1) acc += __shfl_down(acc, off, 64);
    __shared__ double red[4];
    if ((threadIdx.x & 63) == 0) red[threadIdx.x >> 6] = acc;
    __syncthreads();
    if (threadIdx.x == 0)
        out[0] = (float)((red[0] + red[1]) + (red[2] + red[3]));
}

extern "C" void kernel_launch(void* const* d_in, const int* in_sizes, int n_in,
                              void* d_out, int out_size, void* d_ws, size_t ws_size,
                              hipStream_t stream) {
    const float* x = (const float*)d_in[0];
    const float* y = (const float*)d_in[1];
    const float* w = (const float*)d_in[2];
    float* out = (float*)d_out;
    float* partials = (float*)d_ws;  // NPART floats

    mmd_partial_kernel<<<NPART, TPB, 0, stream>>>(x, y, w, partials);
    mmd_reduce_kernel<<<1, 256, 0, stream>>>(partials, out);
}

// Round 3
// 26.820 us; speedup vs baseline: 1.5076x; 1.0109x over previous
//
#include <hip/hip_runtime.h>
#include <hip/hip_bf16.h>
#include <math.h>

// Problem constants (from reference setup_inputs): B=32, N=256, D=32.
#define BB 32
#define NN 256
#define DD 32
#define RPT 4                    // A-rows per thread (held in registers)
#define TPB 64                   // one wave per block; 64*RPT = 256 = all rows
#define SPLIT 32                 // j-dimension split per (batch,type)
#define JCHUNK (NN / SPLIT)      // 8 j's per block
#define NPART (BB * 3 * SPLIT)   // 3072 partials

// type 0: (x,x) weight +1 | type 1: (y,y) weight +1 | type 2: (x,y) weight -2
__global__ __launch_bounds__(TPB) void mmd_partial_kernel(
    const float* __restrict__ x, const float* __restrict__ y,
    const float* __restrict__ w, float* __restrict__ partials) {
    const int blk  = blockIdx.x;
    const int s    = blk & (SPLIT - 1);
    const int bt   = blk / SPLIT;
    const int type = bt % 3;
    const int b    = bt / 3;
    const int tid  = threadIdx.x;

    const float* Arow_base = (type == 1) ? y : x;   // rows (i)
    const float* Bcol_base = (type == 0) ? x : y;   // cols (j)

    // Issue A loads first so their VMEM latency overlaps B staging + barrier.
    // 4 A-rows per thread in registers (+ |a|^2), rows i = r*64 + tid.
    float4 a[RPT][DD / 4];
    #pragma unroll
    for (int r = 0; r < RPT; ++r) {
        const int i = r * TPB + tid;
        const float4* ar =
            (const float4*)(Arow_base + ((size_t)b * NN + i) * DD);
        #pragma unroll
        for (int k = 0; k < DD / 4; ++k) a[r][k] = ar[k];
    }

    // Stage the JCHUNK B-rows in LDS (64 float4 = exactly 1 store/thread).
    __shared__ float4 bs4[JCHUNK * (DD / 4)];
    __shared__ float b2s[JCHUNK];
    {
        const float4* bb =
            (const float4*)(Bcol_base + ((size_t)b * NN + s * JCHUNK) * DD);
        bs4[tid] = bb[tid];
    }

    float a2[RPT];
    #pragma unroll
    for (int r = 0; r < RPT; ++r) {
        float4 s2 = make_float4(0.f, 0.f, 0.f, 0.f);
        #pragma unroll
        for (int k = 0; k < DD / 4; ++k) {
            float4 v = a[r][k];
            s2.x = fmaf(v.x, v.x, s2.x);
            s2.y = fmaf(v.y, v.y, s2.y);
            s2.z = fmaf(v.z, v.z, s2.z);
            s2.w = fmaf(v.w, v.w, s2.w);
        }
        a2[r] = (s2.x + s2.y) + (s2.z + s2.w);
    }

    __syncthreads();
    if (tid < JCHUNK) {
        float4 s2 = make_float4(0.f, 0.f, 0.f, 0.f);
        #pragma unroll
        for (int k = 0; k < DD / 4; ++k) {
            float4 v = bs4[tid * (DD / 4) + k];
            s2.x = fmaf(v.x, v.x, s2.x);
            s2.y = fmaf(v.y, v.y, s2.y);
            s2.z = fmaf(v.z, v.z, s2.z);
            s2.w = fmaf(v.w, v.w, s2.w);
        }
        b2s[tid] = (s2.x + s2.y) + (s2.z + s2.w);
    }
    __syncthreads();

    const float negw_over_d = -w[b] * (1.0f / (float)DD);

    float acc[RPT] = {0.f, 0.f, 0.f, 0.f};
    #pragma unroll
    for (int j = 0; j < JCHUNK; ++j) {
        const float b2 = b2s[j];
        float4 dv[RPT];
        #pragma unroll
        for (int r = 0; r < RPT; ++r) dv[r] = make_float4(0.f, 0.f, 0.f, 0.f);
        #pragma unroll
        for (int k = 0; k < DD / 4; ++k) {
            const float4 bv = bs4[j * (DD / 4) + k];
            #pragma unroll
            for (int r = 0; r < RPT; ++r) {
                dv[r].x = fmaf(a[r][k].x, bv.x, dv[r].x);
                dv[r].y = fmaf(a[r][k].y, bv.y, dv[r].y);
                dv[r].z = fmaf(a[r][k].z, bv.z, dv[r].z);
                dv[r].w = fmaf(a[r][k].w, bv.w, dv[r].w);
            }
        }
        #pragma unroll
        for (int r = 0; r < RPT; ++r) {
            const float dot = (dv[r].x + dv[r].y) + (dv[r].z + dv[r].w);
            float sq = fmaf(-2.0f, dot, a2[r] + b2);
            sq = fmaxf(sq, 0.0f);
            const float nrm = fmaxf(__builtin_amdgcn_sqrtf(sq), 1.0e-4f);
            acc[r] += __expf(negw_over_d * nrm);
        }
    }

    // Deterministic wave64 reduction; lane 0 writes the scaled partial.
    float tsum = (acc[0] + acc[1]) + (acc[2] + acc[3]);
    #pragma unroll
    for (int off = 32; off > 0; off >>= 1) tsum += __shfl_down(tsum, off, 64);
    if (tid == 0) {
        const float weight = (type == 2) ? -2.0f : 1.0f;
        const float scale = weight / ((float)NN * (float)NN * (float)BB);
        partials[blk] = tsum * scale;
    }
}

// Final deterministic reduction of NPART partials in double.
__global__ __launch_bounds__(256) void mmd_reduce_kernel(
    const float* __restrict__ partials, float* __restrict__ out) {
    double acc = 0.0;
    for (int t = threadIdx.x; t < NPART; t += 256) acc += (double)partials[t];
    #pragma unroll
    for (int off = 32; off > 0; off >>= 1) acc += __shfl_down(acc, off, 64);
    __shared__ double red[4];
    if ((threadIdx.x & 63) == 0) red[threadIdx.x >> 6] = acc;
    __syncthreads();
    if (threadIdx.x == 0)
        out[0] = (float)((red[0] + red[1]) + (red[2] + red[3]));
}

extern "C" void kernel_launch(void* const* d_in, const int* in_sizes, int n_in,
                              void* d_out, int out_size, void* d_ws, size_t ws_size,
                              hipStream_t stream) {
    const float* x = (const float*)d_in[0];
    const float* y = (const float*)d_in[1];
    const float* w = (const float*)d_in[2];
    float* out = (float*)d_out;
    float* partials = (float*)d_ws;  // NPART floats

    mmd_partial_kernel<<<NPART, TPB, 0, stream>>>(x, y, w, partials);
    mmd_reduce_kernel<<<1, 256, 0, stream>>>(partials, out);
}

// Round 4
// 23.638 us; speedup vs baseline: 1.7105x; 1.1346x over previous
//
#include <hip/hip_runtime.h>
#include <hip/hip_bf16.h>
#include <math.h>

// Problem constants (from reference setup_inputs): B=32, N=256, D=32.
#define BB 32
#define NN 256
#define DD 32
#define JC 4                       // j-chunks of 64 (one per lane) cover N=256
#define IS 8                       // i-splits per (b,type,jchunk)
#define IC (NN / IS)               // 32 i-rows per block
#define NPART (BB * 3 * JC * IS)   // 3072 partials

__device__ __forceinline__ void fma4(float4& acc, const float4 a, const float4 b) {
    acc.x = fmaf(a.x, b.x, acc.x);
    acc.y = fmaf(a.y, b.y, acc.y);
    acc.z = fmaf(a.z, b.z, acc.z);
    acc.w = fmaf(a.w, b.w, acc.w);
}
__device__ __forceinline__ float red8(const float4 e, const float4 o) {
    return ((e.x + e.y) + (e.z + e.w)) + ((o.x + o.y) + (o.z + o.w));
}

// Lane = one j-row held in registers; i-row is wave-uniform (broadcast loads).
// No LDS, no barriers, ~70 VGPRs.
// type 0: (x,x) +1 | type 1: (y,y) +1 | type 2: (x,y) -2
__global__ __launch_bounds__(64) void mmd_partial_kernel(
    const float* __restrict__ x, const float* __restrict__ y,
    const float* __restrict__ w, float* __restrict__ partials) {
    const int blk  = blockIdx.x;
    const int is   = blk & (IS - 1);
    const int jc   = (blk >> 3) & (JC - 1);
    const int bt   = blk >> 5;
    const int type = bt % 3;
    const int b    = bt / 3;
    const int lane = threadIdx.x;

    const float* Irows = (type == 1) ? y : x;   // rows (i), broadcast
    const float* Jrows = (type == 0) ? x : y;   // cols (j), per-lane

    // Per-lane j-row (j = jc*64 + lane): 8 float4 = 32 VGPRs, loaded once.
    float4 bj[8];
    {
        const float4* jr =
            (const float4*)(Jrows + ((size_t)b * NN + jc * 64 + lane) * DD);
        #pragma unroll
        for (int k = 0; k < 8; ++k) bj[k] = jr[k];
    }

    // Lane l also computes |i-row (i0 + (l&31))|^2 so a2 can be shuffled.
    const int i0 = is * IC;
    float a2l, b2;
    {
        const float4* ir =
            (const float4*)(Irows + ((size_t)b * NN + i0 + (lane & 31)) * DD);
        float4 ae = make_float4(0.f,0.f,0.f,0.f), ao = make_float4(0.f,0.f,0.f,0.f);
        float4 be = make_float4(0.f,0.f,0.f,0.f), bo = make_float4(0.f,0.f,0.f,0.f);
        #pragma unroll
        for (int k = 0; k < 8; k += 2) {
            float4 i_e = ir[k], i_o = ir[k + 1];
            fma4(ae, i_e, i_e);
            fma4(ao, i_o, i_o);
            fma4(be, bj[k], bj[k]);
            fma4(bo, bj[k + 1], bj[k + 1]);
        }
        a2l = red8(ae, ao);   // same accumulation structure as the dot loop
        b2  = red8(be, bo);   // => exact 0 on the xx/yy diagonal before clamp
    }

    const float negw_over_d = -w[b] * (1.0f / (float)DD);

    float acc = 0.f;
    #pragma unroll 2
    for (int ii = 0; ii < IC; ++ii) {
        const float4* av =
            (const float4*)(Irows + ((size_t)b * NN + i0 + ii) * DD);  // uniform
        float4 de = make_float4(0.f,0.f,0.f,0.f), do_ = make_float4(0.f,0.f,0.f,0.f);
        #pragma unroll
        for (int k = 0; k < 8; k += 2) {
            fma4(de,  av[k],     bj[k]);
            fma4(do_, av[k + 1], bj[k + 1]);
        }
        const float dot = red8(de, do_);
        const float a2i = __shfl(a2l, ii, 64);        // uniform index -> readlane
        float sq = fmaf(-2.0f, dot, a2i + b2);
        sq = fmaxf(sq, 1.0e-8f);                      // folds norm clamp: sqrt(1e-8)=1e-4
        const float nrm = __builtin_amdgcn_sqrtf(sq);
        acc += __expf(negw_over_d * nrm);
    }

    // Deterministic wave64 reduction; lane 0 writes the scaled partial.
    #pragma unroll
    for (int off = 32; off > 0; off >>= 1) acc += __shfl_down(acc, off, 64);
    if (lane == 0) {
        const float weight = (type == 2) ? -2.0f : 1.0f;
        const float scale = weight / ((float)NN * (float)NN * (float)BB);
        partials[blk] = acc * scale;
    }
}

// Final deterministic reduction of NPART partials in double.
__global__ __launch_bounds__(256) void mmd_reduce_kernel(
    const float* __restrict__ partials, float* __restrict__ out) {
    double acc = 0.0;
    for (int t = threadIdx.x; t < NPART; t += 256) acc += (double)partials[t];
    #pragma unroll
    for (int off = 32; off > 0; off >>= 1) acc += __shfl_down(acc, off, 64);
    __shared__ double red[4];
    if ((threadIdx.x & 63) == 0) red[threadIdx.x >> 6] = acc;
    __syncthreads();
    if (threadIdx.x == 0)
        out[0] = (float)((red[0] + red[1]) + (red[2] + red[3]));
}

extern "C" void kernel_launch(void* const* d_in, const int* in_sizes, int n_in,
                              void* d_out, int out_size, void* d_ws, size_t ws_size,
                              hipStream_t stream) {
    const float* x = (const float*)d_in[0];
    const float* y = (const float*)d_in[1];
    const float* w = (const float*)d_in[2];
    float* out = (float*)d_out;
    float* partials = (float*)d_ws;  // NPART floats

    mmd_partial_kernel<<<NPART, 64, 0, stream>>>(x, y, w, partials);
    mmd_reduce_kernel<<<1, 256, 0, stream>>>(partials, out);
}